// Round 14
// baseline (134.655 us; speedup 1.0000x reference)
//
#include <hip/hip_runtime.h>
#include <hip/hip_bf16.h>

#define B_NUM 2
#define S_LEN 2048
#define E_DIM 1024
#define H_NUM 16
#define D_DIM 64
#define QKV_LD 3072
// 1/sqrt(64) * log2(e): folded so softmax exp is a bare v_exp_f32 (exp2)
#define QSCALE_LOG2E 0.18033688011112042f

typedef __attribute__((ext_vector_type(8))) short bf16x8;
typedef __attribute__((ext_vector_type(8))) unsigned short u16x8;
typedef __attribute__((ext_vector_type(4))) unsigned short u16x4;
typedef __attribute__((ext_vector_type(4))) float f32x4;
typedef __attribute__((ext_vector_type(16))) float f32x16;
typedef __attribute__((ext_vector_type(2))) int i32x2;

static __device__ __forceinline__ unsigned short f2bf(float f) {
    union { float f; unsigned int u; } v; v.f = f;
    unsigned int r = v.u + 0x7fffu + ((v.u >> 16) & 1u);   // RNE
    return (unsigned short)(r >> 16);
}

static __device__ __forceinline__ float bf2f(unsigned short u) {
    union { unsigned int u; float f; } v; v.u = ((unsigned int)u) << 16;
    return v.f;
}

static __device__ __forceinline__ unsigned cvtpk_bf16(float lo, float hi) {
    unsigned r;
    asm("v_cvt_pk_bf16_f32 %0, %1, %2" : "=v"(r) : "v"(lo), "v"(hi));
    return r;
}

// async global->LDS, 16B per lane; LDS dest = uniform base + lane*16
static __device__ __forceinline__ void gload16(const void* gsrc, void* ldst) {
    __builtin_amdgcn_global_load_lds(
        (const __attribute__((address_space(1))) unsigned int*)gsrc,
        (__attribute__((address_space(3))) unsigned int*)ldst, 16, 0, 0);
}

// ---------------------------------------------------------------------------
// fp32 -> bf16 bulk convert
// ---------------------------------------------------------------------------
__global__ __launch_bounds__(256)
void cvt_f32_bf16(const float* __restrict__ in, unsigned short* __restrict__ outp, int n4) {
    int i = blockIdx.x * blockDim.x + threadIdx.x;
    if (i < n4) {
        float4 f = ((const float4*)in)[i];
        u16x4 o = { f2bf(f.x), f2bf(f.y), f2bf(f.z), f2bf(f.w) };
        ((u16x4*)outp)[i] = o;
    }
}

// ---------------------------------------------------------------------------
// 128x128 bf16 MFMA GEMM, BK=64, 4 waves. (proven rounds 4-13)
// ---------------------------------------------------------------------------
template <bool OUT_BF16, bool QSCALE>
__global__ __launch_bounds__(256)
void gemm_bt_mfma128(const unsigned short* __restrict__ A,
                     const unsigned short* __restrict__ Bw,
                     void* __restrict__ Cv, int M, int N, int K) {
    __shared__ unsigned short As[128 * 64];
    __shared__ unsigned short Bs[128 * 64];
    char* const AsB = (char*)As;
    char* const BsB = (char*)Bs;
    const int tid  = threadIdx.x;
    const int lane = tid & 63;
    const int w    = tid >> 6;
    const int lg   = lane >> 4;
    const int lq   = lane & 15;
    const int bm = blockIdx.y * 128;
    const int bn = blockIdx.x * 128;
    const int wr = (w >> 1) * 64;
    const int wc = (w & 1) * 64;
    const int lrow8 = lane >> 3;
    const int gblk  = (lane & 7) ^ lrow8;

    f32x4 acc[4][4];
#pragma unroll
    for (int i = 0; i < 4; ++i)
#pragma unroll
        for (int j = 0; j < 4; ++j) acc[i][j] = (f32x4){0.f, 0.f, 0.f, 0.f};

    for (int k0 = 0; k0 < K; k0 += 64) {
        __syncthreads();
#pragma unroll
        for (int t = 0; t < 4; ++t) {
            const int c = w * 4 + t;
            const int row = c * 8 + lrow8;
            gload16(A + (size_t)(bm + row) * K + k0 + gblk * 8, AsB + c * 1024);
            gload16(Bw + (size_t)(bn + row) * K + k0 + gblk * 8, BsB + c * 1024);
        }
        __syncthreads();

        bf16x8 af[4][2], bfr[4][2];
#pragma unroll
        for (int rt = 0; rt < 4; ++rt) {
            const int row = wr + rt * 16 + lq;
            const int sz = (row & 7) << 4;
            af[rt][0] = *(const bf16x8*)(AsB + row * 128 + ((lg * 16)      ^ sz));
            af[rt][1] = *(const bf16x8*)(AsB + row * 128 + ((64 + lg * 16) ^ sz));
        }
#pragma unroll
        for (int ct = 0; ct < 4; ++ct) {
            const int row = wc + ct * 16 + lq;
            const int sz = (row & 7) << 4;
            bfr[ct][0] = *(const bf16x8*)(BsB + row * 128 + ((lg * 16)      ^ sz));
            bfr[ct][1] = *(const bf16x8*)(BsB + row * 128 + ((64 + lg * 16) ^ sz));
        }
#pragma unroll
        for (int rt = 0; rt < 4; ++rt)
#pragma unroll
            for (int ct = 0; ct < 4; ++ct) {
                acc[rt][ct] = __builtin_amdgcn_mfma_f32_16x16x32_bf16(af[rt][0], bfr[ct][0], acc[rt][ct], 0, 0, 0);
                acc[rt][ct] = __builtin_amdgcn_mfma_f32_16x16x32_bf16(af[rt][1], bfr[ct][1], acc[rt][ct], 0, 0, 0);
            }
    }

#pragma unroll
    for (int rt = 0; rt < 4; ++rt)
#pragma unroll
        for (int ct = 0; ct < 4; ++ct) {
            const int row = bm + wr + rt * 16 + lg * 4;
            const int col = bn + wc + ct * 16 + lq;
            float scale = 1.f;
            if constexpr (QSCALE) scale = ((col % 192) < 64) ? QSCALE_LOG2E : 1.f;
#pragma unroll
            for (int r = 0; r < 4; ++r) {
                float vv = acc[rt][ct][r] * scale;
                if constexpr (OUT_BF16)
                    ((unsigned short*)Cv)[(size_t)(row + r) * N + col] = f2bf(vv);
                else
                    ((float*)Cv)[(size_t)(row + r) * N + col] = vv;
            }
        }
}

// ---------------------------------------------------------------------------
// 64x64 bf16 MFMA GEMM (known-good; output projection)
// ---------------------------------------------------------------------------
template <bool OUT_BF16, bool QSCALE>
__global__ __launch_bounds__(256)
void gemm_bt_mfma(const unsigned short* __restrict__ A,
                  const unsigned short* __restrict__ Bw,
                  void* __restrict__ Cv, int M, int N, int K) {
    __shared__ unsigned short As[64 * 64];
    __shared__ unsigned short Bs[64 * 64];
    char* const AsB = (char*)As;
    char* const BsB = (char*)Bs;
    const int tid  = threadIdx.x;
    const int lane = tid & 63;
    const int w    = tid >> 6;
    const int lg   = lane >> 4;
    const int lq   = lane & 15;
    const int bm = blockIdx.y * 64;
    const int bn = blockIdx.x * 64;
    const int wr = (w >> 1) * 32;
    const int wc = (w & 1) * 32;
    const int sr = tid >> 2;
    const int sc = (tid & 3) * 16;
    const int swzS = (sr & 7) << 4;

    f32x4 acc[2][2];
#pragma unroll
    for (int i = 0; i < 2; ++i)
#pragma unroll
        for (int j = 0; j < 2; ++j) acc[i][j] = (f32x4){0.f, 0.f, 0.f, 0.f};

    const unsigned short* ap = A  + (size_t)(bm + sr) * K + sc;
    const unsigned short* bp = Bw + (size_t)(bn + sr) * K + sc;

    for (int k0 = 0; k0 < K; k0 += 64) {
        __syncthreads();
        u16x8 av0 = *(const u16x8*)(ap + k0);
        u16x8 av1 = *(const u16x8*)(ap + k0 + 8);
        u16x8 bv0 = *(const u16x8*)(bp + k0);
        u16x8 bv1 = *(const u16x8*)(bp + k0 + 8);
        *(u16x8*)(AsB + sr * 128 + ((sc * 2)      ^ swzS)) = av0;
        *(u16x8*)(AsB + sr * 128 + ((sc * 2 + 16) ^ swzS)) = av1;
        *(u16x8*)(BsB + sr * 128 + ((sc * 2)      ^ swzS)) = bv0;
        *(u16x8*)(BsB + sr * 128 + ((sc * 2 + 16) ^ swzS)) = bv1;
        __syncthreads();

        bf16x8 af[2][2], bfr[2][2];
#pragma unroll
        for (int rt = 0; rt < 2; ++rt) {
            const int row = wr + rt * 16 + lq;
            const int sz = (row & 7) << 4;
            af[rt][0] = *(const bf16x8*)(AsB + row * 128 + ((lg * 16)      ^ sz));
            af[rt][1] = *(const bf16x8*)(AsB + row * 128 + ((64 + lg * 16) ^ sz));
        }
#pragma unroll
        for (int ct = 0; ct < 2; ++ct) {
            const int row = wc + ct * 16 + lq;
            const int sz = (row & 7) << 4;
            bfr[ct][0] = *(const bf16x8*)(BsB + row * 128 + ((lg * 16)      ^ sz));
            bfr[ct][1] = *(const bf16x8*)(BsB + row * 128 + ((64 + lg * 16) ^ sz));
        }
#pragma unroll
        for (int rt = 0; rt < 2; ++rt)
#pragma unroll
            for (int ct = 0; ct < 2; ++ct) {
                acc[rt][ct] = __builtin_amdgcn_mfma_f32_16x16x32_bf16(af[rt][0], bfr[ct][0], acc[rt][ct], 0, 0, 0);
                acc[rt][ct] = __builtin_amdgcn_mfma_f32_16x16x32_bf16(af[rt][1], bfr[ct][1], acc[rt][ct], 0, 0, 0);
            }
    }

#pragma unroll
    for (int rt = 0; rt < 2; ++rt)
#pragma unroll
        for (int ct = 0; ct < 2; ++ct) {
            const int row = bm + wr + rt * 16 + lg * 4;
            const int col = bn + wc + ct * 16 + lq;
            float scale = 1.f;
            if constexpr (QSCALE) scale = ((col % 192) < 64) ? QSCALE_LOG2E : 1.f;
#pragma unroll
            for (int r = 0; r < 4; ++r) {
                float vv = acc[rt][ct][r] * scale;
                if constexpr (OUT_BF16)
                    ((unsigned short*)Cv)[(size_t)(row + r) * N + col] = f2bf(vv);
                else
                    ((float*)Cv)[(size_t)(row + r) * N + col] = vv;
            }
        }
}

// ---------------------------------------------------------------------------
// Flash attention v14: KV-SPLIT x2 on the modern no-max body.
// Diagnosis (r12 ablation + r13 null): per-wave issue stream ~2700cyc of
// serialized multi-pipe work; all pipes <=40%; only 2 waves/SIMD (grid 512
// = 2 blocks/CU). Fix TLP without duplicating staging or shrinking chains:
// split keys across 2 blocks (part 0: keys [0,1024), part 1: [1024,2048)),
// grid 1024 -> 4 blocks/CU. LDS trimmed to 36,864B (K 2buf + V 2buf +
// 1024-entry bias slice) so 4 blocks/CU are LDS-legal.
// Each block: 16 tiles of 64 keys, v6-style dbuf + 1 __syncthreads/tile.
// Output: normalized bf16 partial O + f32 rsum; exact linear merge after.
// ---------------------------------------------------------------------------
__global__ __launch_bounds__(256)
void attn_v14(const unsigned short* __restrict__ qkv, const int* __restrict__ mask,
              unsigned short* __restrict__ Po, float* __restrict__ Zp) {
    __shared__ __align__(16) char KsP[2][8192];
    __shared__ __align__(16) char VtP[2][8192];
    __shared__ __align__(16) float BiasF[1024];

    const int tid  = threadIdx.x;
    const int lane = tid & 63;
    const int w    = tid >> 6;
    const int ln   = lane & 31;
    const int hi   = lane >> 5;
    const int part = blockIdx.x & 1;
    const int q0   = (blockIdx.x >> 1) * 128;
    const int h  = blockIdx.y;
    const int b  = blockIdx.z;
    const int kvbase = part * 1024;
    const unsigned short* const kv =
        qkv + (size_t)b * S_LEN * QKV_LD + (size_t)h * (3 * D_DIM);

    {   // stage this part's bias half: 1024 floats, 256 threads x 4
        const int4* mr = (const int4*)(mask + (size_t)b * S_LEN + kvbase);
        int4 m0 = mr[tid];
        float4 f0 = { m0.x ? 0.f : -30000.f, m0.y ? 0.f : -30000.f,
                      m0.z ? 0.f : -30000.f, m0.w ? 0.f : -30000.f };
        ((float4*)BiasF)[tid] = f0;
    }

    // Q B-frags (pre-scaled by 0.125*log2e)
    bf16x8 qf[4];
    {
        const unsigned short* qp = kv + (size_t)(q0 + w * 32 + ln) * QKV_LD + hi * 8;
#pragma unroll
        for (int kk = 0; kk < 4; ++kk)
            qf[kk] = *(const bf16x8*)(qp + kk * 16);
    }

    const int lrow8 = lane >> 3;
    const int gblk  = (lane & 7) ^ lrow8;   // pre-swizzled 16B block for K stage
    const int vkb = (tid & 15) * 4;         // V staging key base
    const int vdb = (tid >> 4) * 4;         // V staging d base

    // ---- stage tile 0 into buffer 0 ----
    {
#pragma unroll
        for (int t = 0; t < 2; ++t) {
            const int c = w * 2 + t;
            gload16(kv + (size_t)(kvbase + c * 8 + lrow8) * QKV_LD + D_DIM + gblk * 8,
                    KsP[0] + c * 1024);
        }
        u16x4 vr[4];
#pragma unroll
        for (int i = 0; i < 4; ++i)
            vr[i] = *(const u16x4*)(kv + (size_t)(kvbase + vkb + i) * QKV_LD + 2 * D_DIM + vdb);
#pragma unroll
        for (int j = 0; j < 4; ++j) {
            u16x4 o = { vr[0][j], vr[1][j], vr[2][j], vr[3][j] };
            const int row = vdb + j;
            *(u16x4*)(VtP[0] + row * 128 + ((vkb * 2) ^ ((row & 7) << 4))) = o;
        }
    }
    __syncthreads();

    f32x16 accO[2];
#pragma unroll
    for (int dt = 0; dt < 2; ++dt)
#pragma unroll
        for (int r = 0; r < 16; ++r) accO[dt][r] = 0.f;
    f32x4 rsumv = (f32x4){0.f, 0.f, 0.f, 0.f};

    const int NT = 16;   // 1024 keys / 64
    for (int it = 0; it < NT; ++it) {
        const int cur = it & 1;
        const int kv0l = it * 64;              // local bias offset
        const int kvg  = kvbase + it * 64;     // global key base
        char* const KsC = KsP[cur];
        char* const VtC = VtP[cur];
        const bool pf = (it + 1 < NT);

        // ---- prefetch tile it+1 (issue only) ----
        u16x4 vr[4];
        if (pf) {
            const int kvn = kvg + 64;
#pragma unroll
            for (int t = 0; t < 2; ++t) {
                const int c = w * 2 + t;
                gload16(kv + (size_t)(kvn + c * 8 + lrow8) * QKV_LD + D_DIM + gblk * 8,
                        KsP[cur ^ 1] + c * 1024);
            }
#pragma unroll
            for (int i = 0; i < 4; ++i)
                vr[i] = *(const u16x4*)(kv + (size_t)(kvn + vkb + i) * QKV_LD + 2 * D_DIM + vdb);
        }

        // ---- S^T = K Q^T + bias (log2 domain) ----
        f32x16 s[2];
#pragma unroll
        for (int ks = 0; ks < 2; ++ks)
#pragma unroll
            for (int m = 0; m < 4; ++m) {
                f32x4 b4 = *(const f32x4*)(&BiasF[kv0l + ks * 32 + m * 8 + hi * 4]);
#pragma unroll
                for (int i = 0; i < 4; ++i) s[ks][m * 4 + i] = b4[i];
            }
        __builtin_amdgcn_s_setprio(1);
#pragma unroll
        for (int ks = 0; ks < 2; ++ks) {
            const int krow = ks * 32 + ln;
            const int swz = (ln & 7) << 4;
#pragma unroll
            for (int kk = 0; kk < 4; ++kk) {
                bf16x8 kf = *(const bf16x8*)(KsC + krow * 128 + (((kk * 16 + hi * 8) * 2) ^ swz));
                s[ks] = __builtin_amdgcn_mfma_f32_32x32x16_bf16(kf, qf[kk], s[ks], 0, 0, 0);
            }
        }
        __builtin_amdgcn_s_setprio(0);

        // ---- p = exp2(s); row-sum accumulators ----
#pragma unroll
        for (int ks = 0; ks < 2; ++ks)
#pragma unroll
            for (int r = 0; r < 16; ++r) {
                float p = __builtin_amdgcn_exp2f(s[ks][r]);
                s[ks][r] = p;
                rsumv[r & 3] += p;
            }

        // ---- assemble P^T B-frags in-register ----
        bf16x8 pb[4];
#pragma unroll
        for (int ks = 0; ks < 2; ++ks) {
            unsigned wA[4], wB[4];
#pragma unroll
            for (int m = 0; m < 4; ++m) {
                wA[m] = cvtpk_bf16(s[ks][4 * m + 0], s[ks][4 * m + 1]);
                wB[m] = cvtpk_bf16(s[ks][4 * m + 2], s[ks][4 * m + 3]);
            }
#pragma unroll
            for (int t = 0; t < 2; ++t) {
                i32x2 ra = __builtin_amdgcn_permlane32_swap((int)wA[2 * t], (int)wA[2 * t + 1], false, false);
                i32x2 rb = __builtin_amdgcn_permlane32_swap((int)wB[2 * t], (int)wB[2 * t + 1], false, false);
                union { unsigned u[4]; bf16x8 v; } uu;
                uu.u[0] = (unsigned)ra[0];
                uu.u[1] = (unsigned)rb[0];
                uu.u[2] = (unsigned)ra[1];
                uu.u[3] = (unsigned)rb[1];
                pb[ks * 2 + t] = uu.v;
            }
        }

        // ---- O^T += V^T P^T ----
        __builtin_amdgcn_s_setprio(1);
#pragma unroll
        for (int dt = 0; dt < 2; ++dt) {
            const int drow = dt * 32 + ln;
            const int swz = (ln & 7) << 4;
#pragma unroll
            for (int n = 0; n < 4; ++n) {
                bf16x8 va = *(const bf16x8*)(VtC + drow * 128 + (((n * 16 + hi * 8) * 2) ^ swz));
                accO[dt] = __builtin_amdgcn_mfma_f32_32x32x16_bf16(va, pb[n], accO[dt], 0, 0, 0);
            }
        }
        __builtin_amdgcn_s_setprio(0);

        // ---- complete V prefetch: regs -> LDS (transposed, swizzled) ----
        if (pf) {
#pragma unroll
            for (int j = 0; j < 4; ++j) {
                u16x4 o = { vr[0][j], vr[1][j], vr[2][j], vr[3][j] };
                const int row = vdb + j;
                *(u16x4*)(VtP[cur ^ 1] + row * 128 + ((vkb * 2) ^ ((row & 7) << 4))) = o;
            }
        }
        __syncthreads();   // drains gload_lds + ds_writes; flips buffers
    }

    // ---- partial epilogue: normalized bf16 O + f32 rsum ----
    float rsum = rsumv[0] + rsumv[1] + rsumv[2] + rsumv[3];
    {
        i32x2 rr = __builtin_amdgcn_permlane32_swap(__float_as_int(rsum), __float_as_int(rsum), false, false);
        rsum = __int_as_float(rr[0]) + __int_as_float(rr[1]);
    }
    const int q = q0 + w * 32 + ln;
    const float inv = 1.f / rsum;
    unsigned short* po = Po + (((size_t)(part * B_NUM + b) * H_NUM + h) * S_LEN + q) * D_DIM;
#pragma unroll
    for (int dt = 0; dt < 2; ++dt)
#pragma unroll
        for (int m = 0; m < 4; ++m) {
            u16x4 o;
#pragma unroll
            for (int i = 0; i < 4; ++i) o[i] = f2bf(accO[dt][4 * m + i] * inv);
            *(u16x4*)(po + dt * 32 + m * 8 + hi * 4) = o;
        }
    if (hi == 0)
        Zp[((size_t)(part * B_NUM + b) * H_NUM + h) * S_LEN + q] = rsum;
}

// ---------------------------------------------------------------------------
// Merge the two KV-half partials into vbuf (B,S,E) bf16, e = h*64+d.
// Weights are rsum fractions (exact linear combine of normalized partials).
// ---------------------------------------------------------------------------
__global__ __launch_bounds__(256)
void attn_merge(const unsigned short* __restrict__ Po, const float* __restrict__ Zp,
                unsigned short* __restrict__ vbuf) {
    const int idx = blockIdx.x * 256 + threadIdx.x;   // 0 .. B*S*H*8-1
    const int j   = idx & 7;
    const int rh  = idx >> 3;          // (b*S+q)*H + h
    const int h   = rh & (H_NUM - 1);
    const int bq  = rh >> 4;           // b*S + q
    const int b   = bq >> 11;
    const int q   = bq & (S_LEN - 1);

    const size_t prow0 = ((size_t)(b)          * H_NUM + h) * S_LEN + q;
    const size_t prow1 = ((size_t)(B_NUM + b)  * H_NUM + h) * S_LEN + q;
    const float rs0 = Zp[prow0];
    const float rs1 = Zp[prow1];
    const float is = 1.f / (rs0 + rs1);
    const float w0 = rs0 * is;
    const float w1 = rs1 * is;

    u16x8 a = *(const u16x8*)(Po + prow0 * D_DIM + j * 8);
    u16x8 c = *(const u16x8*)(Po + prow1 * D_DIM + j * 8);
    u16x8 o;
#pragma unroll
    for (int k = 0; k < 8; ++k)
        o[k] = f2bf(bf2f(a[k]) * w0 + bf2f(c[k]) * w1);
    *(u16x8*)(vbuf + (size_t)bq * E_DIM + h * D_DIM + j * 8) = o;
}

// ---------------------------------------------------------------------------
extern "C" void kernel_launch(void* const* d_in, const int* in_sizes, int n_in,
                              void* d_out, int out_size, void* d_ws, size_t ws_size,
                              hipStream_t stream) {
    const float* x      = (const float*)d_in[0];
    const int*   mask   = (const int*)d_in[1];
    const float* w_qkv  = (const float*)d_in[2];
    const float* w_o    = (const float*)d_in[3];
    float*       out    = (float*)d_out;

    const int M = B_NUM * S_LEN;     // 4096
    unsigned short* qkvb = (unsigned short*)d_ws;                    // M x 3E
    unsigned short* vbuf = qkvb + (size_t)M * 3 * E_DIM;             // M x E
    unsigned short* xb   = vbuf + (size_t)M * E_DIM;                 // M x E
    unsigned short* wqb  = xb   + (size_t)M * E_DIM;                 // 3E x E
    unsigned short* wob  = wqb  + (size_t)3 * E_DIM * E_DIM;         // E x E
    unsigned short* Po   = wob  + (size_t)E_DIM * E_DIM;             // 2*M*E bf16
    float*          Zp   = (float*)(Po + (size_t)2 * M * E_DIM);     // 2*B*H*S f32

    dim3 blk(256);
    {
        int n4;
        n4 = M * E_DIM / 4;
        cvt_f32_bf16<<<dim3((n4 + 255) / 256), blk, 0, stream>>>(x, xb, n4);
        n4 = 3 * E_DIM * E_DIM / 4;
        cvt_f32_bf16<<<dim3((n4 + 255) / 256), blk, 0, stream>>>(w_qkv, wqb, n4);
        n4 = E_DIM * E_DIM / 4;
        cvt_f32_bf16<<<dim3((n4 + 255) / 256), blk, 0, stream>>>(w_o, wob, n4);
    }

    // QKV projection (q columns pre-scaled by 0.125*log2e), bf16 out
    gemm_bt_mfma128<true, true><<<dim3(3 * E_DIM / 128, M / 128), blk, 0, stream>>>(
        xb, wqb, qkvb, M, 3 * E_DIM, E_DIM);

    // flash attention v14: KV-split x2, grid 1024 (4 blocks/CU)
    attn_v14<<<dim3((S_LEN / 128) * 2, H_NUM, B_NUM), blk, 0, stream>>>(
        qkvb, mask, Po, Zp);

    // merge partials -> vbuf
    attn_merge<<<dim3(B_NUM * S_LEN * H_NUM * 8 / 256), blk, 0, stream>>>(Po, Zp, vbuf);

    // output projection, fp32 out
    gemm_bt_mfma<false, false><<<dim3(E_DIM / 64, M / 64), blk, 0, stream>>>(
        vbuf, wob, out, M, E_DIM, E_DIM);
}